// Round 12
// baseline (361.736 us; speedup 1.0000x reference)
//
#include <hip/hip_runtime.h>
#include <stdint.h>

#define NF 8192
#define NX 2048
#define MROWS 8192
#define NGROUPS 32
#define NSTEP 64   // NX/32 K-steps

typedef unsigned short u16;
typedef __bf16 bf16x8 __attribute__((ext_vector_type(8)));
typedef float f32x4 __attribute__((ext_vector_type(4)));

#define AS1 __attribute__((address_space(1)))
#define AS3 __attribute__((address_space(3)))

// async global->LDS, 16B/lane; LDS dest = wave-uniform base + lane*16.
__device__ __forceinline__ void glds16(const void* g, void* l) {
    __builtin_amdgcn_global_load_lds((AS1 void*)(uintptr_t)g,
                                     (AS3 void*)(uintptr_t)l, 16, 0, 0);
}

__device__ __forceinline__ u16 f2bf(float f) {
    unsigned u = __float_as_uint(f);
    return (u16)((u + 0x7FFFu + ((u >> 16) & 1u)) >> 16);  // RNE
}

// packed [NF, NX/2] (one byte per int32, two nibbles) -> W bf16 [NF, NX] row-major.
__global__ void dequant_kernel(const int* __restrict__ packed,
                               const float* __restrict__ scales,
                               const int* __restrict__ zeros,
                               uint32_t* __restrict__ W2) {
    int tid = blockIdx.x * blockDim.x + threadIdx.x;   // [0, NF*NX/2)
    int f = tid >> 10;          // NX/2 = 1024 per row
    int i = tid & 1023;
    int g = f * NGROUPS + (i >> 5);
    int p = packed[tid];
    float s = scales[g];
    float z = (float)zeros[g];
    float w0 = ((float)(p & 15) - z) * s;
    float w1 = ((float)((p >> 4) & 15) - z) * s;
    W2[tid] = (uint32_t)f2bf(w0) | ((uint32_t)f2bf(w1) << 16);
}

// x fp32 -> bf16, 4 elems/thread
__global__ void cvt_kernel(const float4* __restrict__ x, ushort4* __restrict__ y) {
    int i = blockIdx.x * blockDim.x + threadIdx.x;
    float4 v = x[i];
    ushort4 o;
    o.x = f2bf(v.x); o.y = f2bf(v.y); o.z = f2bf(v.z); o.w = f2bf(v.w);
    y[i] = o;
}

// ===========================================================================
// 128x128 tile, 4 waves (2Mx2N, 64x64/wave), BK=32, mfma_f32_16x16x32_bf16.
// THREE independent blocks per CU (3 waves/SIMD of cross-block TLP -- the
// only overlap mechanism that measured real in 11 rounds; R6's 2-stream
// version hit 264us gemm at 1.10x work).  LDS ring-3 of 16 KiB regions =
// 48 KiB/block (3 blocks = 144 <= 160).  __launch_bounds__(256,3) caps
// VGPR at 170 (need ~150: acc 64 + frags 32 + addr).
//
// LDS region (16 KiB): A at +0 (128 rows), B at +8192 (128 rows).
// Row = 64 B (32 k bf16) = 4 x 16B units; content(row, phys u) = k-slot
// u ^ ((row>>1)&3)  (R7/R8's exact form, measured 0 conflicts):
//   write: glds linear, unit U = t + 256c: row = 64c + (t>>2), phys = t&3,
//          source k-slot = (t&3) ^ ((t>>3)&3)   (64c drops mod 4).
//   read:  row = base16 + l15 (base16 %16==0), phys = quad ^ ((l15>>1)&3)
//          -> 16-lane-period zero-conflict family.
//
// Per step s (regC = data(s); regT receives s+2):
//   BAR                        // stage(s) visible (own VMCNT4@s-1 + BAR)
//   issue 8 ds_reads (a0-3,b0,b1 | FENCE | b2,b3); 4 glds stage(s+2)->regT
//     WAR: regT's readers (s-1) LGKM0-drained before their j23 MFMAs, pre-BAR.
//   LGKM2 -> a0-3,b0,b1 ready: MFMA j=0,1 (8)   [setprio]
//   LGKM0 -> b2,b3 ready:      MFMA j=2,3 (8)   [setprio]
//   VMCNT4                     // drains stage(s+1) (oldest 4), leaves s+2
// Tail: s=NSTEP-2 -> VMCNT0; s=NSTEP-1 -> none.
// ===========================================================================

#define BAR    __builtin_amdgcn_s_barrier()
#define LGKM2  asm volatile("s_waitcnt lgkmcnt(2)" ::: "memory")
#define LGKM0  asm volatile("s_waitcnt lgkmcnt(0)" ::: "memory")
#define VMCNT4 asm volatile("s_waitcnt vmcnt(4)" ::: "memory")
#define VMCNT0 asm volatile("s_waitcnt vmcnt(0)" ::: "memory")
#define FENCE  __builtin_amdgcn_sched_barrier(0)

#define LD8(off) (*(const bf16x8*)(smem + (off)))

#define MFMA(d, va, vb) d = __builtin_amdgcn_mfma_f32_16x16x32_bf16(va, vb, d, 0, 0, 0)

#define STAGE4(REG, S) do { \
    const char* _sa = srcA + (size_t)(S) * 64; \
    const char* _sb = srcB + (size_t)(S) * 64; \
    glds16(_sa,          smem + (REG) + t16); \
    glds16(_sa + 262144, smem + (REG) + 4096  + t16); \
    glds16(_sb,          smem + (REG) + 8192  + t16); \
    glds16(_sb + 262144, smem + (REG) + 12288 + t16); \
} while (0)

__global__ __launch_bounds__(256, 3)
void gemm_kernel(const u16* __restrict__ A, const u16* __restrict__ B,
                 const float* __restrict__ bias, float* __restrict__ C) {
    __shared__ __align__(16) char smem[49152];   // 3 x 16 KiB ring

    const int t = threadIdx.x;

    // T1: striped XCD swizzle (R6 verbatim). Grid 4096 = 64 by x 64 bx;
    // each XCD owns 8 by-rows as 4 supers of (2 by x 64 bx), by fastest.
    const int bid = blockIdx.x;
    const int xcd = bid & 7;
    const int local = bid >> 3;          // 0..511
    const int super = local >> 7;        // 0..3
    const int r = local & 127;
    const int by = xcd * 8 + super * 2 + (r & 1);   // 0..63
    const int bx = r >> 1;                          // 0..63
    const int rowA0 = by * 128;
    const int rowB0 = bx * 128;

    // ---- staging addressing (inverse-swizzled global source, linear LDS) ----
    const int t16 = t * 16;
    const int kslot = (t & 3) ^ ((t >> 3) & 3);
    const char* srcA = (const char*)A + (size_t)(rowA0 + (t >> 2)) * 4096 + kslot * 16;
    const char* srcB = (const char*)B + (size_t)(rowB0 + (t >> 2)) * 4096 + kslot * 16;

    // ---- fragment read addressing (16-lane-period zero-conflict form) ----
    const int lane = t & 63;
    const int wv = t >> 6;
    const int wm = wv >> 1;            // 0..1 (M half, 64 rows)
    const int wn = wv & 1;             // 0..1 (N half, 64 cols)
    const int l15 = lane & 15;
    const int quad = lane >> 4;        // 0..3 = k-slot this lane consumes
    const int uX = (quad ^ ((l15 >> 1) & 3)) << 4;
    const int aOff = (wm * 64 + l15) * 64 + uX;          // + i*1024
    const int bOff = 8192 + (wn * 64 + l15) * 64 + uX;   // + j*1024

    f32x4 acc[4][4];
#pragma unroll
    for (int i = 0; i < 4; ++i)
#pragma unroll
        for (int j = 0; j < 4; ++j) acc[i][j] = {0.f, 0.f, 0.f, 0.f};

    bf16x8 a[4], b[4];

    // ---- prologue: stage steps 0,1 into regions 0,1; drain step0 ----
    STAGE4(0,     0);
    STAGE4(16384, 1);
    VMCNT4;            // stage(0) done (own); BAR at loop top publishes

    int regC = 0, regN = 16384, regT = 32768;

#pragma unroll 1
    for (int s = 0; s < NSTEP; ++s) {
        FENCE; BAR; FENCE;
        // reads: a0-3, b0, b1 (gate LGKM2) | b2, b3 (gate LGKM0)
#pragma unroll
        for (int i = 0; i < 4; ++i) a[i] = LD8(regC + aOff + i * 1024);
        b[0] = LD8(regC + bOff);
        b[1] = LD8(regC + bOff + 1024);
        FENCE;   // pin DS order: first 6 complete before last 2
        b[2] = LD8(regC + bOff + 2048);
        b[3] = LD8(regC + bOff + 3072);
        FENCE;
        if (s + 2 < NSTEP) STAGE4(regT, s + 2);   // vmcnt-side; WAR-safe post-BAR
        FENCE; LGKM2; FENCE;                      // a0-3,b0,b1 ready
        __builtin_amdgcn_s_setprio(1);
#pragma unroll
        for (int j = 0; j < 2; ++j)
#pragma unroll
            for (int i = 0; i < 4; ++i) MFMA(acc[i][j], a[i], b[j]);
        __builtin_amdgcn_s_setprio(0);
        FENCE; LGKM0; FENCE;                      // b2,b3 ready (hid under MFMAs)
        __builtin_amdgcn_s_setprio(1);
#pragma unroll
        for (int j = 2; j < 4; ++j)
#pragma unroll
            for (int i = 0; i < 4; ++i) MFMA(acc[i][j], a[i], b[j]);
        __builtin_amdgcn_s_setprio(0);
        FENCE;
        if (s + 2 < NSTEP) VMCNT4;                // stage(s+1) landed
        else if (s + 1 < NSTEP) VMCNT0;           // last stage draining

        const int tmp = regC; regC = regN; regN = regT; regT = tmp;
    }

    // ---- epilogue: C/D col = l15, row = quad*4 + e (m89/m91) ----
    const int col0 = rowB0 + wn * 64 + l15;
    const int row0 = rowA0 + wm * 64 + quad * 4;
    float bj[4];
#pragma unroll
    for (int j = 0; j < 4; ++j) bj[j] = bias[col0 + j * 16];
#pragma unroll
    for (int i = 0; i < 4; ++i) {
#pragma unroll
        for (int e = 0; e < 4; ++e) {
            float* crow = C + (size_t)(row0 + i * 16 + e) * NF;
#pragma unroll
            for (int j = 0; j < 4; ++j)
                __builtin_nontemporal_store(acc[i][j][e] + bj[j], crow + col0 + j * 16);
        }
    }
}

extern "C" void kernel_launch(void* const* d_in, const int* in_sizes, int n_in,
                              void* d_out, int out_size, void* d_ws, size_t ws_size,
                              hipStream_t stream) {
    const float* x      = (const float*)d_in[0];   // [4,2048,2048] fp32
    const int* packed   = (const int*)d_in[1];     // [8192,1024]
    const float* scales = (const float*)d_in[2];   // [8192,32]
    const int* zeros    = (const int*)d_in[3];     // [8192,32]
    const float* bias   = (const float*)d_in[4];   // [8192]
    float* out = (float*)d_out;                    // [8192, 8192] fp32

    // workspace: W bf16 (32 MiB) + x bf16 (32 MiB); fully rewritten every call
    u16* Wq = (u16*)d_ws;
    u16* Xb = Wq + (size_t)NF * NX;

    dequant_kernel<<<(NF * (NX / 2)) / 256, 256, 0, stream>>>(packed, scales, zeros, (uint32_t*)Wq);
    cvt_kernel<<<(MROWS * NX / 4) / 256, 256, 0, stream>>>((const float4*)x, (ushort4*)Xb);

    gemm_kernel<<<dim3((MROWS / 128) * (NF / 128)), 256, 0, stream>>>(Xb, Wq, bias, out);
}

// Round 14
// 302.188 us; speedup vs baseline: 1.1971x; 1.1971x over previous
//
#include <hip/hip_runtime.h>
#include <stdint.h>

#define NF 8192
#define NX 2048
#define MROWS 8192
#define NGROUPS 32
#define NSTEP 64        // NX/32 K-steps
#define RSTRIDE 32768   // ring region stride (32 KiB)

typedef unsigned short u16;
typedef __bf16 bf16x8 __attribute__((ext_vector_type(8)));
typedef float f32x4 __attribute__((ext_vector_type(4)));

#define AS1 __attribute__((address_space(1)))
#define AS3 __attribute__((address_space(3)))

// async global->LDS, 16B/lane; LDS dest = wave-uniform base + lane*16.
__device__ __forceinline__ void glds16(const void* g, void* l) {
    __builtin_amdgcn_global_load_lds((AS1 void*)(uintptr_t)g,
                                     (AS3 void*)(uintptr_t)l, 16, 0, 0);
}

__device__ __forceinline__ u16 f2bf(float f) {
    unsigned u = __float_as_uint(f);
    return (u16)((u + 0x7FFFu + ((u >> 16) & 1u)) >> 16);  // RNE
}

// packed [NF, NX/2] (one byte per int32, two nibbles) -> W bf16 [NF, NX] row-major.
__global__ void dequant_kernel(const int* __restrict__ packed,
                               const float* __restrict__ scales,
                               const int* __restrict__ zeros,
                               uint32_t* __restrict__ W2) {
    int tid = blockIdx.x * blockDim.x + threadIdx.x;   // [0, NF*NX/2)
    int f = tid >> 10;          // NX/2 = 1024 per row
    int i = tid & 1023;
    int g = f * NGROUPS + (i >> 5);
    int p = packed[tid];
    float s = scales[g];
    float z = (float)zeros[g];
    float w0 = ((float)(p & 15) - z) * s;
    float w1 = ((float)((p >> 4) & 15) - z) * s;
    W2[tid] = (uint32_t)f2bf(w0) | ((uint32_t)f2bf(w1) << 16);
}

// x fp32 -> bf16, 4 elems/thread
__global__ void cvt_kernel(const float4* __restrict__ x, ushort4* __restrict__ y) {
    int i = blockIdx.x * blockDim.x + threadIdx.x;
    float4 v = x[i];
    ushort4 o;
    o.x = f2bf(v.x); o.y = f2bf(v.y); o.z = f2bf(v.z); o.w = f2bf(v.w);
    y[i] = o;
}

// ===========================================================================
// 256x256 tile, 8 waves (2Mx4N, wave 128x64), BK=32 steps, ring-4 x 32 KiB,
// mfma_f32_16x16x32_bf16.  TRUE SOFTWARE PIPELINE: step s issues the 12
// ds_reads for step s+1, then gates MFMA(s) on LGKMCNT(12) -- which (DS
// in-order) drains exactly the reads issued at s-1.  MFMA has NO dependency
// on same-step reads: the LDS pipe processes pre-reads DURING the MFMA
// window, removing the read->wait->MFMA serial chain that capped R10/R12.
//
// Ring-4 + 3-ahead staging ledger (4 glds/step, glds are vmcnt-only):
//   prologue: stage r0,r1,r2 (12); VMCNT4 leaves stage(2) -> data(0),(1)
//             published by BAR; read frags(0) -> bank A (12, ungated).
//   step s:   BAR (publishes data(s+1): its stage drained at end of s-1)
//             pre-read frags(s+1) from r((s+1)&3) -> NXT bank [if s+1<64]
//             issue stage(s+3) -> r((s+3)&3)      [if s+3<64]
//               WAR: r(s+3)=r(s-1); its readers hit their LGKM12 gate at
//               step s-1 (before MFMA(s-1)), two barriers before this write.
//             LGKM12 (s<63) / LGKM0 (s=63): frags(s) ready, new 12 in flight
//             setprio(1); 32 MFMA on CUR bank; setprio(0)
//             s<=60: VMCNT4 (drains stage(s+2), leaves stage(s+3));
//             s==61: VMCNT0 (drains stage(63)); s>=62: none.
//   banks alternate via 2x-unrolled loop (static names, rule #20).
//
// LDS region (32 KiB): A 256 rows at +0, B 256 rows at +16384; row = 64 B
// = 4 x 16B units; content(row, phys u) = k-slot u ^ ((row>>1)&3) (R7/R8/R12
// form, measured 0 conflicts).  Write: glds linear, thread t -> row t>>2
// (+128/chunk), phys t&3, source k-slot (t&3)^((t>>3)&3).  Read: row =
// base + i*16 + l15, phys = quad ^ ((l15>>1)&3) -> 16-lane-period family.
//
// Budget/CU/step: LDS 96KB rd + 32KB wr ~= 1280 cyc CONCURRENT with MFMA
// 1032 cyc -> wall ~1400 vs R10's serialized ~2600.  VGPR: 128 acc(AGPR) +
// 96 frag banks + ~25 addr ~= 250 <= 256 cap @(512,2) -- spill = failure mode.
//
// Hang audit (post R13 infra failure): all waves execute identical BAR
// counts; every waitcnt is monotonically satisfiable; no atomics/spins;
// 1024 independent blocks.  No deadlock path -- resubmitted unchanged.
// ===========================================================================

#define BAR    __builtin_amdgcn_s_barrier()
#define LGKM12 asm volatile("s_waitcnt lgkmcnt(12)" ::: "memory")
#define LGKM0  asm volatile("s_waitcnt lgkmcnt(0)" ::: "memory")
#define VMCNT4 asm volatile("s_waitcnt vmcnt(4)" ::: "memory")
#define VMCNT0 asm volatile("s_waitcnt vmcnt(0)" ::: "memory")
#define FENCE  __builtin_amdgcn_sched_barrier(0)

#define LD8(off) (*(const bf16x8*)(smem + (off)))

#define MFMA(d, va, vb) d = __builtin_amdgcn_mfma_f32_16x16x32_bf16(va, vb, d, 0, 0, 0)

// 4 glds/thread/step: A rows 0-127, 128-255; B rows 0-127, 128-255.
#define STAGE4(REG, S) do { \
    const char* _sa = srcA + (size_t)(S) * 64; \
    const char* _sb = srcB + (size_t)(S) * 64; \
    glds16(_sa,          smem + (REG) + t16); \
    glds16(_sa + 524288, smem + (REG) + 8192  + t16); \
    glds16(_sb,          smem + (REG) + 16384 + t16); \
    glds16(_sb + 524288, smem + (REG) + 24576 + t16); \
} while (0)

#define STEP(S, CA, CB, NA, NB) do { \
    FENCE; BAR; FENCE; \
    if ((S) + 1 < NSTEP) { \
        const int rN = (((S) + 1) & 3) * RSTRIDE; \
        _Pragma("unroll") \
        for (int i_ = 0; i_ < 8; ++i_) NA[i_] = LD8(rN + aOff + i_ * 1024); \
        _Pragma("unroll") \
        for (int j_ = 0; j_ < 4; ++j_) NB[j_] = LD8(rN + bOff + j_ * 1024); \
    } \
    FENCE; \
    if ((S) + 3 < NSTEP) STAGE4((((S) + 3) & 3) * RSTRIDE, (S) + 3); \
    FENCE; \
    if ((S) + 1 < NSTEP) { LGKM12; } else { LGKM0; } \
    FENCE; \
    __builtin_amdgcn_s_setprio(1); \
    _Pragma("unroll") \
    for (int i_ = 0; i_ < 8; ++i_) \
        _Pragma("unroll") \
        for (int j_ = 0; j_ < 4; ++j_) MFMA(acc[i_][j_], CA[i_], CB[j_]); \
    __builtin_amdgcn_s_setprio(0); \
    FENCE; \
    if ((S) <= NSTEP - 4) { VMCNT4; } \
    else if ((S) == NSTEP - 3) { VMCNT0; } \
} while (0)

__global__ __launch_bounds__(512, 2)
void gemm_kernel(const u16* __restrict__ A, const u16* __restrict__ B,
                 const float* __restrict__ bias, float* __restrict__ C) {
    __shared__ __align__(16) char smem[131072];   // ring-4 x 32 KiB

    const int t = threadIdx.x;

    // T1: striped XCD swizzle (R10 verbatim). Grid 1024 = 32 by x 32 bx.
    const int bid = blockIdx.x;
    const int xcd = bid & 7;
    const int local = bid >> 3;          // 0..127
    const int super = local >> 6;        // 0..1
    const int r = local & 63;
    const int by = xcd * 4 + super * 2 + (r & 1);   // 0..31
    const int bx = r >> 1;                          // 0..31
    const int rowA0 = by * 256;
    const int rowB0 = bx * 256;

    // ---- staging addressing (inverse-swizzled global source, linear LDS) ----
    const int t16 = t * 16;
    const int kslot = (t & 3) ^ ((t >> 3) & 3);
    const char* srcA = (const char*)A + (size_t)(rowA0 + (t >> 2)) * 4096 + kslot * 16;
    const char* srcB = (const char*)B + (size_t)(rowB0 + (t >> 2)) * 4096 + kslot * 16;

    // ---- fragment read addressing (16-lane-period zero-conflict form) ----
    const int lane = t & 63;
    const int wv = t >> 6;
    const int wm = wv >> 2;            // 0..1 (M half, 128 rows)
    const int wn = wv & 3;             // 0..3 (N quarter, 64 cols)
    const int l15 = lane & 15;
    const int quad = lane >> 4;        // k-slot this lane consumes
    const int uX = (quad ^ ((l15 >> 1) & 3)) << 4;
    const int aOff = (wm * 128 + l15) * 64 + uX;           // + i*1024
    const int bOff = 16384 + (wn * 64 + l15) * 64 + uX;    // + j*1024

    f32x4 acc[8][4];
#pragma unroll
    for (int i = 0; i < 8; ++i)
#pragma unroll
        for (int j = 0; j < 4; ++j) acc[i][j] = {0.f, 0.f, 0.f, 0.f};

    bf16x8 aA[8], bA[4], aB[8], bB[4];

    // ---- prologue: stage steps 0,1,2 -> r0,r1,r2; publish 0,1; read frags(0) ----
    STAGE4(0,           0);
    STAGE4(RSTRIDE,     1);
    STAGE4(2 * RSTRIDE, 2);
    VMCNT4;             // drains stages 0,1 (oldest 8), leaves stage(2)
    BAR;                // publish data(0), data(1)
#pragma unroll
    for (int i = 0; i < 8; ++i) aA[i] = LD8(aOff + i * 1024);
#pragma unroll
    for (int j = 0; j < 4; ++j) bA[j] = LD8(bOff + j * 1024);
    // ungated: STEP(0)'s LGKM12 (24 -> 12 outstanding) gates these 12.

#pragma unroll 1
    for (int s = 0; s < NSTEP; s += 2) {
        STEP(s,     aA, bA, aB, bB);
        STEP(s + 1, aB, bB, aA, bA);
    }

    // ---- epilogue: C/D col = l15, row = quad*4 + e (m89/m91) ----
    const int col0 = rowB0 + wn * 64 + l15;
    const int row0 = rowA0 + wm * 128 + quad * 4;
    float bj[4];
#pragma unroll
    for (int j = 0; j < 4; ++j) bj[j] = bias[col0 + j * 16];
#pragma unroll
    for (int i = 0; i < 8; ++i) {
#pragma unroll
        for (int e = 0; e < 4; ++e) {
            float* crow = C + (size_t)(row0 + i * 16 + e) * NF;
#pragma unroll
            for (int j = 0; j < 4; ++j)
                __builtin_nontemporal_store(acc[i][j][e] + bj[j], crow + col0 + j * 16);
        }
    }
}

extern "C" void kernel_launch(void* const* d_in, const int* in_sizes, int n_in,
                              void* d_out, int out_size, void* d_ws, size_t ws_size,
                              hipStream_t stream) {
    const float* x      = (const float*)d_in[0];   // [4,2048,2048] fp32
    const int* packed   = (const int*)d_in[1];     // [8192,1024]
    const float* scales = (const float*)d_in[2];   // [8192,32]
    const int* zeros    = (const int*)d_in[3];     // [8192,32]
    const float* bias   = (const float*)d_in[4];   // [8192]
    float* out = (float*)d_out;                    // [8192, 8192] fp32

    // workspace: W bf16 (32 MiB) + x bf16 (32 MiB); fully rewritten every call
    u16* Wq = (u16*)d_ws;
    u16* Xb = Wq + (size_t)NF * NX;

    dequant_kernel<<<(NF * (NX / 2)) / 256, 256, 0, stream>>>(packed, scales, zeros, (uint32_t*)Wq);
    cvt_kernel<<<(MROWS * NX / 4) / 256, 256, 0, stream>>>((const float4*)x, (ushort4*)Xb);

    gemm_kernel<<<dim3((MROWS / 256) * (NF / 256)), 512, 0, stream>>>(Xb, Wq, bias, out);
}

// Round 16
// 276.948 us; speedup vs baseline: 1.3062x; 1.0911x over previous
//
#include <hip/hip_runtime.h>
#include <stdint.h>

#define NF 8192
#define NX 2048
#define MROWS 8192
#define NGROUPS 32
#define NT 32   // NX/64 K-tiles

typedef unsigned short u16;
typedef __bf16 bf16x8 __attribute__((ext_vector_type(8)));
typedef float f32x4 __attribute__((ext_vector_type(4)));

#define AS1 __attribute__((address_space(1)))
#define AS3 __attribute__((address_space(3)))

// async global->LDS, 16B/lane; LDS dest = wave-uniform base + lane*16.
__device__ __forceinline__ void glds16(const void* g, void* l) {
    __builtin_amdgcn_global_load_lds((AS1 void*)(uintptr_t)g,
                                     (AS3 void*)(uintptr_t)l, 16, 0, 0);
}

__device__ __forceinline__ u16 f2bf(float f) {
    unsigned u = __float_as_uint(f);
    return (u16)((u + 0x7FFFu + ((u >> 16) & 1u)) >> 16);  // RNE
}

// packed [NF, NX/2] (one byte per int32, two nibbles) -> W bf16 [NF, NX] row-major.
__global__ void dequant_kernel(const int* __restrict__ packed,
                               const float* __restrict__ scales,
                               const int* __restrict__ zeros,
                               uint32_t* __restrict__ W2) {
    int tid = blockIdx.x * blockDim.x + threadIdx.x;   // [0, NF*NX/2)
    int f = tid >> 10;          // NX/2 = 1024 per row
    int i = tid & 1023;
    int g = f * NGROUPS + (i >> 5);
    int p = packed[tid];
    float s = scales[g];
    float z = (float)zeros[g];
    float w0 = ((float)(p & 15) - z) * s;
    float w1 = ((float)((p >> 4) & 15) - z) * s;
    W2[tid] = (uint32_t)f2bf(w0) | ((uint32_t)f2bf(w1) << 16);
}

// x fp32 -> bf16, 4 elems/thread
__global__ void cvt_kernel(const float4* __restrict__ x, ushort4* __restrict__ y) {
    int i = blockIdx.x * blockDim.x + threadIdx.x;
    float4 v = x[i];
    ushort4 o;
    o.x = f2bf(v.x); o.y = f2bf(v.y); o.z = f2bf(v.z); o.w = f2bf(v.w);
    y[i] = o;
}

// ===========================================================================
// R10 verbatim (best total: 284.5 us, conflicts 0, WRITE anomaly 344 MB)
// with ONE variable changed: plain C-stores instead of nontemporal.
// Theory: nt-stores bypass L2 write-combining; at the 256^2 geometry the two
// 64B half-lines of each 128B C-line leave as separate partial-line HBM
// transactions (WRITE_SIZE 344 vs 262 ideal; R6's 128^2 stayed clean at
// 278).  Plain stores let L2 merge them.  Risk: C-stream L2 pollution
// raising FETCH -- operand hot set ~1 MB/XCD vs 4 MB L2, headroom exists.
//
// (Resubmit of round 15: pod died with UnresponsiveContainer before running;
// kernel differs from the measured-good R10 only in the epilogue store
// instruction -- no hang path exists.)
//
// 256x256 tile, 8 waves (2Mx4N, wave tile 128x64), BK=64,
// mfma_f32_16x16x32_bf16, ONE block/CU (LDS dbuf 2 x 64 KiB).
// ONE barrier + one vmcnt(0) per K-tile; lgkm-split gating (LGKM8 -> k0
// MFMAs run while k1's reads complete).
//
// LDS buffer (64 KiB): A at +0 (256 lines), B at +32768 (256 lines).
// Line = 128 B = one row's BK=64 bf16, 8 x 16B units (zero-conflict family,
// measured 0 in R1/R6/R7/R8/R10):
//   content(line, phys u) = k-unit u ^ (line&7); k-byte(u) = (u>>2)*64+(u&3)*16.
//   write: glds linear, unit U = t + 512c: line = (t>>3)+64c, phys = t&7;
//          source k-unit ulog = (t&7)^((t>>3)&7), row = (t>>3)+64c.
//   read:  line = base + i*16 + l15, phys = (kk*4+quad)^(l15&7)
//          -> 16-lane-period form; lanes hit distinct banks.
//
// Per K-tile T (bo active, so inactive):
//   BAR; issue a0[8],b0[4] (kk0); 8 glds stage(T+1)->so; issue a1[8] (kk1)
//   LGKM8 -> a0,b0 done; MFMA k0 j=0,1
//   issue b1[4]; MFMA k0 j=2,3
//   LGKM0 -> a1,b1 done; MFMA k1 (32)
//   VMCNT0  // own 8 stages for T+1 landed (had the whole tile to fly)
// ===========================================================================

#define BAR    __builtin_amdgcn_s_barrier()
#define LGKM8  asm volatile("s_waitcnt lgkmcnt(8)" ::: "memory")
#define LGKM0  asm volatile("s_waitcnt lgkmcnt(0)" ::: "memory")
#define VMCNT0 asm volatile("s_waitcnt vmcnt(0)" ::: "memory")
#define FENCE  __builtin_amdgcn_sched_barrier(0)

#define LD8(off) (*(const bf16x8*)(smem + (off)))

#define MFMA(d, va, vb) d = __builtin_amdgcn_mfma_f32_16x16x32_bf16(va, vb, d, 0, 0, 0)

// 8 glds/thread: A 4 chunks of 64 rows, then B 4 chunks (chunk stride 64*4096B)
#define STAGE8(BUF, KOFF) do { \
    glds16(srcA + (KOFF),          smem + (BUF) + t16); \
    glds16(srcA + 262144 + (KOFF), smem + (BUF) + 8192  + t16); \
    glds16(srcA + 524288 + (KOFF), smem + (BUF) + 16384 + t16); \
    glds16(srcA + 786432 + (KOFF), smem + (BUF) + 24576 + t16); \
    glds16(srcB + (KOFF),          smem + (BUF) + 32768 + t16); \
    glds16(srcB + 262144 + (KOFF), smem + (BUF) + 40960 + t16); \
    glds16(srcB + 524288 + (KOFF), smem + (BUF) + 49152 + t16); \
    glds16(srcB + 786432 + (KOFF), smem + (BUF) + 57344 + t16); \
} while (0)

__global__ __launch_bounds__(512, 2)
void gemm_kernel(const u16* __restrict__ A, const u16* __restrict__ B,
                 const float* __restrict__ bias, float* __restrict__ C) {
    __shared__ __align__(16) char smem[131072];   // 2 x 64 KiB dbuf

    const int t = threadIdx.x;

    // T1: striped XCD swizzle. Grid 1024 = 32 by x 32 bx; each XCD owns
    // 4 by-rows as 2 supers of (2 by x 32 bx), by fastest.
    const int bid = blockIdx.x;
    const int xcd = bid & 7;
    const int local = bid >> 3;          // 0..127
    const int super = local >> 6;        // 0..1
    const int r = local & 63;
    const int by = xcd * 4 + super * 2 + (r & 1);   // 0..31
    const int bx = r >> 1;                          // 0..31
    const int rowA0 = by * 256;
    const int rowB0 = bx * 256;

    // ---- staging addressing (inverse-swizzled global source, linear LDS) ----
    const int t16 = t * 16;
    const int ulog = (t & 7) ^ ((t >> 3) & 7);
    const int koffS = (ulog >> 2) * 64 + (ulog & 3) * 16;
    const char* srcA = (const char*)A + (size_t)(rowA0 + (t >> 3)) * 4096 + koffS;
    const char* srcB = (const char*)B + (size_t)(rowB0 + (t >> 3)) * 4096 + koffS;

    // ---- fragment read addressing (16-lane-period zero-conflict form) ----
    const int lane = t & 63;
    const int wv = t >> 6;
    const int wm = wv >> 2;            // 0..1 (M half, 128 rows)
    const int wn = wv & 3;             // 0..3 (N quarter, 64 cols)
    const int l15 = lane & 15;
    const int quad = lane >> 4;
    const int l7 = l15 & 7;
    const int sx0 = (quad ^ l7) << 4;        // kk=0 unit
    const int sx1 = ((4 + quad) ^ l7) << 4;  // kk=1 unit
    const int aOff = (wm * 128 + l15) * 128;           // + i*2048
    const int bOff = 32768 + (wn * 64 + l15) * 128;    // + j*2048

    f32x4 acc[8][4];
#pragma unroll
    for (int i = 0; i < 8; ++i)
#pragma unroll
        for (int j = 0; j < 4; ++j) acc[i][j] = {0.f, 0.f, 0.f, 0.f};

    bf16x8 a0[8], a1[8], b0[4], b1[4];

    // ---- prologue: stage tile0 -> buf0; own-drain; BAR at loop top ----
    STAGE8(0, 0);
    VMCNT0;

#pragma unroll 1
    for (int T = 0; T < NT; ++T) {
        const int bo = (T & 1) << 16;   // active buffer
        const int so = bo ^ 65536;      // inactive (receives T+1)

        FENCE; BAR; FENCE;
        // kk0 reads (12 DS)
#pragma unroll
        for (int i = 0; i < 8; ++i) a0[i] = LD8(bo + aOff + i * 2048 + sx0);
#pragma unroll
        for (int j = 0; j < 4; ++j) b0[j] = LD8(bo + bOff + j * 2048 + sx0);
        FENCE;
        if (T + 1 < NT) STAGE8(so, (T + 1) * 128);   // vmcnt-side; WAR-safe post-BAR
        FENCE;
        // kk1 A reads (8 DS)
#pragma unroll
        for (int i = 0; i < 8; ++i) a1[i] = LD8(bo + aOff + i * 2048 + sx1);
        FENCE; LGKM8; FENCE;            // a0,b0 ready (oldest 12 of 20)
        __builtin_amdgcn_s_setprio(1);
#pragma unroll
        for (int j = 0; j < 2; ++j)
#pragma unroll
            for (int i = 0; i < 8; ++i) MFMA(acc[i][j], a0[i], b0[j]);
        __builtin_amdgcn_s_setprio(0);
        FENCE;
        // kk1 B reads (4 DS) -- issued late to cap frag liveness
#pragma unroll
        for (int j = 0; j < 4; ++j) b1[j] = LD8(bo + bOff + j * 2048 + sx1);
        FENCE;
        __builtin_amdgcn_s_setprio(1);
#pragma unroll
        for (int j = 2; j < 4; ++j)
#pragma unroll
            for (int i = 0; i < 8; ++i) MFMA(acc[i][j], a0[i], b0[j]);
        __builtin_amdgcn_s_setprio(0);
        FENCE; LGKM0; FENCE;            // a1,b1 ready (hid under k0 MFMAs)
        __builtin_amdgcn_s_setprio(1);
#pragma unroll
        for (int j = 0; j < 4; ++j)
#pragma unroll
            for (int i = 0; i < 8; ++i) MFMA(acc[i][j], a1[i], b1[j]);
        __builtin_amdgcn_s_setprio(0);
        FENCE;
        if (T + 1 < NT) VMCNT0;         // own 8 stages for T+1 landed
    }

    // ---- epilogue: C/D col = l15, row = quad*4 + e (m89/m91) ----
    // Plain stores (NOT nontemporal): let L2 write-combine the j=0/j=1
    // 64B halves of each 128B line (R10's nt version measured 344 MB
    // WRITE_SIZE vs 262 ideal).
    const int col0 = rowB0 + wn * 64 + l15;
    const int row0 = rowA0 + wm * 128 + quad * 4;
    float bj[4];
#pragma unroll
    for (int j = 0; j < 4; ++j) bj[j] = bias[col0 + j * 16];
#pragma unroll
    for (int i = 0; i < 8; ++i) {
#pragma unroll
        for (int e = 0; e < 4; ++e) {
            float* crow = C + (size_t)(row0 + i * 16 + e) * NF;
#pragma unroll
            for (int j = 0; j < 4; ++j)
                crow[col0 + j * 16] = acc[i][j][e] + bj[j];
        }
    }
}

extern "C" void kernel_launch(void* const* d_in, const int* in_sizes, int n_in,
                              void* d_out, int out_size, void* d_ws, size_t ws_size,
                              hipStream_t stream) {
    const float* x      = (const float*)d_in[0];   // [4,2048,2048] fp32
    const int* packed   = (const int*)d_in[1];     // [8192,1024]
    const float* scales = (const float*)d_in[2];   // [8192,32]
    const int* zeros    = (const int*)d_in[3];     // [8192,32]
    const float* bias   = (const float*)d_in[4];   // [8192]
    float* out = (float*)d_out;                    // [8192, 8192] fp32

    // workspace: W bf16 (32 MiB) + x bf16 (32 MiB); fully rewritten every call
    u16* Wq = (u16*)d_ws;
    u16* Xb = Wq + (size_t)NF * NX;

    dequant_kernel<<<(NF * (NX / 2)) / 256, 256, 0, stream>>>(packed, scales, zeros, (uint32_t*)Wq);
    cvt_kernel<<<(MROWS * NX / 4) / 256, 256, 0, stream>>>((const float4*)x, (ushort4*)Xb);

    gemm_kernel<<<dim3((MROWS / 256) * (NF / 256)), 512, 0, stream>>>(Xb, Wq, bias, out);
}